// Round 7
// baseline (149.945 us; speedup 1.0000x reference)
//
#include <hip/hip_runtime.h>
#include <hip/hip_bf16.h>
#include <cstdint>

#define NN 100000
#define DEG 16
#define FF 256
#define UU 128

typedef __attribute__((ext_vector_type(8))) short short8;
typedef __attribute__((ext_vector_type(4))) float f32x4;
typedef __attribute__((ext_vector_type(4))) unsigned int u32x4;  // asm-pinnable (uint4 is a struct -> "indirect" asm operand, won't compile)

__device__ __forceinline__ unsigned short f2bf(float x) {
    uint32_t u = __builtin_bit_cast(uint32_t, x);
    uint32_t r = (u + 0x7fffu + ((u >> 16) & 1u)) >> 16;
    return (unsigned short)r;
}
__device__ __forceinline__ float bf2f(unsigned short b) {
    return __builtin_bit_cast(float, (uint32_t)b << 16);
}
__device__ __forceinline__ uint32_t cvt_pk_bf16(float lo, float hi) {
    uint32_t r;
    asm("v_cvt_pk_bf16_f32 %0, %1, %2" : "=v"(r) : "v"(lo), "v"(hi));
    return r;
}

// Pre-kernel: W [256][128] f32 -> Wt [128][256] bf16 (transposed, 64 KB, L2-hot).
__global__ void k_convW(const float* __restrict__ W, unsigned short* __restrict__ Wt) {
    int i = blockIdx.x * 256 + threadIdx.x;  // 32768 elements
    int k = i >> 7, c = i & 127;
    Wt[c * 256 + k] = f2bf(W[i]);
}

// GEMM: h = ns @ W via bf16 MFMA. 32 rows x 128 cols per block, 4 waves, wave
// w owns cols [w*32, w*32+32). NO LDS staging, NO barriers in the main loop:
// each wave loads A direct from global (all 4 waves read the same 32 rows ->
// L1 serves the redundancy), depth-2 software pipeline, fp32->bf16 via
// v_cvt_pk_bf16_f32. B fragments pinned in VGPRs (round-3/5 lesson: unpinned
// batches get rolled into the loop and serialize on VMEM latency).
__global__ __launch_bounds__(256, 3) void k_gemm(
    const float* __restrict__ ns, const unsigned short* __restrict__ Wt,
    const float* __restrict__ ka, unsigned short* __restrict__ hb,
    float* __restrict__ a_src, float* __restrict__ a_dst)
{
    __shared__ char smem[32 * 136 * 2 + 1024];  // Ht[32][136] ushort + ka[256] f32
    float* ka_s = (float*)(smem + 32 * 136 * 2);
    const int t = threadIdx.x;
    const int lane = t & 63;
    const int w = t >> 6;
    const int row0 = blockIdx.x * 32;        // 3125 * 32 = 100000 exact
    const int lrow = lane & 15;
    const int khalf = lane >> 4;

    ka_s[t] = ka[t];

    // ---- B fragments: bfrag[nt][ks], (lane,elem)->k = khalf*8 + ks*32 + e ----
    short8 bfrag[2][8];
    {
        const int col0 = w * 32 + lrow;
        #pragma unroll
        for (int nt = 0; nt < 2; ++nt) {
            const unsigned short* wp = Wt + (size_t)(col0 + nt * 16) * 256 + khalf * 8;
            #pragma unroll
            for (int ks = 0; ks < 8; ++ks)
                bfrag[nt][ks] = *(const short8*)(wp + ks * 32);
        }
    }
    #pragma unroll
    for (int nt = 0; nt < 2; ++nt)
        #pragma unroll
        for (int ks = 0; ks < 8; ++ks)
            asm volatile("" : "+v"(bfrag[nt][ks]));  // pin

    // ---- A row pointers: same (lane,elem)->k map as B ----
    const float* arow[2];
    #pragma unroll
    for (int mt = 0; mt < 2; ++mt)
        arow[mt] = ns + (size_t)(row0 + mt * 16 + lrow) * FF + khalf * 8;

    f32x4 acc[2][2];
    #pragma unroll
    for (int mt = 0; mt < 2; ++mt)
        #pragma unroll
        for (int nt = 0; nt < 2; ++nt)
            acc[mt][nt] = (f32x4){0.f, 0.f, 0.f, 0.f};

    // ---- K-loop: depth-2 pipelined direct-global A, no barriers ----
    f32x4 c0[2], c1[2], n0[2], n1[2];
    #pragma unroll
    for (int mt = 0; mt < 2; ++mt) {
        c0[mt] = *(const f32x4*)(arow[mt]);
        c1[mt] = *(const f32x4*)(arow[mt] + 4);
    }
    #pragma unroll
    for (int ks = 0; ks < 8; ++ks) {
        if (ks < 7) {
            #pragma unroll
            for (int mt = 0; mt < 2; ++mt) {
                n0[mt] = *(const f32x4*)(arow[mt] + (ks + 1) * 32);
                n1[mt] = *(const f32x4*)(arow[mt] + (ks + 1) * 32 + 4);
            }
        }
        short8 a[2];
        #pragma unroll
        for (int mt = 0; mt < 2; ++mt) {
            u32x4 u;
            u[0] = cvt_pk_bf16(c0[mt][0], c0[mt][1]);
            u[1] = cvt_pk_bf16(c0[mt][2], c0[mt][3]);
            u[2] = cvt_pk_bf16(c1[mt][0], c1[mt][1]);
            u[3] = cvt_pk_bf16(c1[mt][2], c1[mt][3]);
            a[mt] = __builtin_bit_cast(short8, u);
        }
        #pragma unroll
        for (int mt = 0; mt < 2; ++mt)
            #pragma unroll
            for (int nt = 0; nt < 2; ++nt)
                acc[mt][nt] = __builtin_amdgcn_mfma_f32_16x16x32_bf16(
                    a[mt], bfrag[nt][ks], acc[mt][nt], 0, 0, 0);
        #pragma unroll
        for (int mt = 0; mt < 2; ++mt) { c0[mt] = n0[mt]; c1[mt] = n1[mt]; }
    }

    // ---- acc -> Ht (stride 136 shorts breaks bank aliasing) ----
    unsigned short* Hs = (unsigned short*)smem;
    {
        const int wcol = w * 32;
        #pragma unroll
        for (int mt = 0; mt < 2; ++mt)
            #pragma unroll
            for (int nt = 0; nt < 2; ++nt)
                #pragma unroll
                for (int r = 0; r < 4; ++r) {
                    int row = mt * 16 + khalf * 4 + r;
                    int col = wcol + nt * 16 + lrow;
                    Hs[row * 136 + col] = f2bf(acc[mt][nt][r]);
                }
    }
    __syncthreads();

    // ---- coalesced hb store + attention dots (8 threads per row) ----
    {
        const int row = t >> 3, q8 = t & 7;
        const int gr = row0 + row;
        short8 hv0 = *(const short8*)(Hs + row * 136 + q8 * 16);
        short8 hv1 = *(const short8*)(Hs + row * 136 + q8 * 16 + 8);
        float ps = 0.f, pd = 0.f;
        #pragma unroll
        for (int e = 0; e < 8; ++e) {
            int c = q8 * 16 + e;
            ps = fmaf(bf2f((unsigned short)hv0[e]), ka_s[c], ps);
            pd = fmaf(bf2f((unsigned short)hv0[e]), ka_s[UU + c], pd);
            ps = fmaf(bf2f((unsigned short)hv1[e]), ka_s[c + 8], ps);
            pd = fmaf(bf2f((unsigned short)hv1[e]), ka_s[UU + c + 8], pd);
        }
        short8* op = (short8*)(hb + (size_t)gr * UU + q8 * 16);
        op[0] = hv0;
        op[1] = hv1;
        ps += __shfl_xor(ps, 1, 64); ps += __shfl_xor(ps, 2, 64); ps += __shfl_xor(ps, 4, 64);
        pd += __shfl_xor(pd, 1, 64); pd += __shfl_xor(pd, 2, 64); pd += __shfl_xor(pd, 4, 64);
        if (q8 == 0) { a_src[gr] = ps; a_dst[gr] = pd; }
    }
}

// Edge kernel: scores + per-node softmax -> packed nd[e] = (dst<<15) | norm_q15.
// 16 consecutive threads = one node (src sorted, exactly DEG=16 edges/node).
__global__ __launch_bounds__(256, 8) void k_edge(
    const int* __restrict__ edges, const float* __restrict__ ew,
    const float* __restrict__ a_src, const float* __restrict__ a_dst,
    uint32_t* __restrict__ nd)
{
    const int ei = blockIdx.x * 256 + threadIdx.x;
    const int n = ei >> 4;
    const int dst = edges[2 * ei + 1];
    const float w = ew[ei];
    const float x0 = w * (a_src[n] + a_dst[dst]);
    float x = x0 > 0.f ? x0 : 0.2f * x0;        // leaky_relu, slope 0.2
    x = fminf(2.f, fmaxf(-2.f, x));             // clip
    const float s = __expf(x);

    float ssum = s;                              // xor masks <16 stay in-group
    ssum += __shfl_xor(ssum, 1, 64);
    ssum += __shfl_xor(ssum, 2, 64);
    ssum += __shfl_xor(ssum, 4, 64);
    ssum += __shfl_xor(ssum, 8, 64);
    const float norm = s / ssum;

    uint32_t q15 = (uint32_t)(norm * 32768.f + 0.5f);
    if (q15 > 32767u) q15 = 32767u;
    nd[ei] = ((uint32_t)dst << 15) | q15;
}

// Aggregation: 4 nodes per wave, 16 lanes per node, lane q owns 16B (8 bf16
// dims). All 16 row-loads issued back-to-back, then PINNED via opaque asm so
// the compiler cannot roll them into the FMA loop (round-5 post-mortem:
// VGPR=60 proved r[16] was serialized, ~6.9us/wave = 16 serial cache misses).
// Pin j only forces a progressive vmcnt(15-j) drain; all 16 stay in flight.
__global__ __launch_bounds__(256, 4) void k_agg(
    const uint32_t* __restrict__ nd, const unsigned short* __restrict__ hb,
    float* __restrict__ out)
{
    const int t = threadIdx.x;
    const int lane = t & 63;
    const int wv = t >> 6;
    const int g = lane >> 4;
    const int q = lane & 15;
    const int n = blockIdx.x * 16 + wv * 4 + g;   // 6250*16 = 100000 exact

    const uint32_t v = nd[(size_t)n * DEG + q];   // this lane's edge
    const uint32_t dstB = (v >> 15) << 8;         // dst * 256 bytes
    const float normf = (float)(v & 32767u) * (1.f / 32768.f);
    const int gb = lane & 48;

    // addresses for all 16 edges of this node
    uint32_t ab[16];
    #pragma unroll
    for (int j = 0; j < 16; ++j) ab[j] = __shfl(dstB, gb | j, 64);

    // batch-issue 16 independent 16B gathers
    const char* hbase = (const char*)hb + q * 16;
    u32x4 r[16];
    #pragma unroll
    for (int j = 0; j < 16; ++j) r[j] = *(const u32x4*)(hbase + ab[j]);

    // norm broadcast overlaps with load latency (LDS pipe, independent of vmcnt)
    float nf[16];
    #pragma unroll
    for (int j = 0; j < 16; ++j) nf[j] = __shfl(normf, gb | j, 64);

    // pin all 16 results live (placed AFTER all issues; u32x4 = legal "v" quad)
    #pragma unroll
    for (int j = 0; j < 16; ++j) asm volatile("" : "+v"(r[j]));

    float acc[8];
    #pragma unroll
    for (int d = 0; d < 8; ++d) acc[d] = 0.f;
    #pragma unroll
    for (int j = 0; j < 16; ++j) {
        acc[0] = fmaf(nf[j], __builtin_bit_cast(float, r[j][0] << 16), acc[0]);
        acc[1] = fmaf(nf[j], __builtin_bit_cast(float, r[j][0] & 0xffff0000u), acc[1]);
        acc[2] = fmaf(nf[j], __builtin_bit_cast(float, r[j][1] << 16), acc[2]);
        acc[3] = fmaf(nf[j], __builtin_bit_cast(float, r[j][1] & 0xffff0000u), acc[3]);
        acc[4] = fmaf(nf[j], __builtin_bit_cast(float, r[j][2] << 16), acc[4]);
        acc[5] = fmaf(nf[j], __builtin_bit_cast(float, r[j][2] & 0xffff0000u), acc[5]);
        acc[6] = fmaf(nf[j], __builtin_bit_cast(float, r[j][3] << 16), acc[6]);
        acc[7] = fmaf(nf[j], __builtin_bit_cast(float, r[j][3] & 0xffff0000u), acc[7]);
    }

    float* op = out + (size_t)n * UU + q * 8;
    float4 o0, o1;
    o0.x = acc[0]; o0.y = acc[1]; o0.z = acc[2]; o0.w = acc[3];
    o1.x = acc[4]; o1.y = acc[5]; o1.z = acc[6]; o1.w = acc[7];
    *(float4*)op = o0;
    *(float4*)(op + 4) = o1;
}

extern "C" void kernel_launch(void* const* d_in, const int* in_sizes, int n_in,
                              void* d_out, int out_size, void* d_ws, size_t ws_size,
                              hipStream_t stream) {
    const float* ns    = (const float*)d_in[0];  // [1, N, 256] f32
    const int*   edges = (const int*)d_in[1];    // [1, E, 2] i32, src sorted
    const float* ew    = (const float*)d_in[2];  // [1, E] f32
    const float* W     = (const float*)d_in[3];  // [256, 128] f32
    const float* ka    = (const float*)d_in[4];  // [256, 1] f32
    float* out = (float*)d_out;                  // [N, 128] f32

    char* ws = (char*)d_ws;
    unsigned short* hb = (unsigned short*)ws;                    // N*128 bf16 = 25.6 MB
    float* a_src = (float*)(ws + (size_t)NN * UU * 2);           // N f32
    float* a_dst = a_src + NN;                                   // N f32
    unsigned short* Wt = (unsigned short*)(ws + (size_t)NN * UU * 2 + 2 * (size_t)NN * 4);  // 64 KB
    uint32_t* nd = (uint32_t*)(ws + (size_t)NN * UU * 2 + 2 * (size_t)NN * 4 + 65536);      // E u32 = 6.4 MB

    k_convW<<<FF * UU / 256, 256, 0, stream>>>(W, Wt);                        // 128 blocks
    k_gemm<<<NN / 32, 256, 0, stream>>>(ns, Wt, ka, hb, a_src, a_dst);        // 3125 blocks
    k_edge<<<NN * DEG / 256, 256, 0, stream>>>(edges, ew, a_src, a_dst, nd);  // 6250 blocks
    k_agg<<<NN / 16, 256, 0, stream>>>(nd, hb, out);                          // 6250 blocks
}

// Round 8
// 149.429 us; speedup vs baseline: 1.0035x; 1.0035x over previous
//
#include <hip/hip_runtime.h>
#include <hip/hip_bf16.h>
#include <cstdint>

#define NN 100000
#define DEG 16
#define FF 256
#define UU 128

typedef __attribute__((ext_vector_type(8))) short short8;
typedef __attribute__((ext_vector_type(4))) float f32x4;
typedef __attribute__((ext_vector_type(4))) unsigned int u32x4;

// Single asm, 8 tied operands: all 8 values must be live HERE simultaneously,
// so all 8 producing loads must issue before this point. (Round-7 lesson:
// per-value pins let the scheduler serialize load->pin->use chains.)
#define PIN8(a,b,c,d,e,f,g,h) asm volatile("" : "+v"(a),"+v"(b),"+v"(c),"+v"(d),"+v"(e),"+v"(f),"+v"(g),"+v"(h))

__device__ __forceinline__ unsigned short f2bf(float x) {
    uint32_t u = __builtin_bit_cast(uint32_t, x);
    uint32_t r = (u + 0x7fffu + ((u >> 16) & 1u)) >> 16;
    return (unsigned short)r;
}
__device__ __forceinline__ float bf2f(unsigned short b) {
    return __builtin_bit_cast(float, (uint32_t)b << 16);
}
__device__ __forceinline__ uint32_t cvt_pk_bf16(float lo, float hi) {
    uint32_t r;
    asm("v_cvt_pk_bf16_f32 %0, %1, %2" : "=v"(r) : "v"(lo), "v"(hi));
    return r;
}

// Pre-kernel: W [256][128] f32 -> Wt [128][256] bf16 (transposed, 64 KB, L2-hot).
__global__ void k_convW(const float* __restrict__ W, unsigned short* __restrict__ Wt) {
    int i = blockIdx.x * 256 + threadIdx.x;  // 32768 elements
    int k = i >> 7, c = i & 127;
    Wt[c * 256 + k] = f2bf(W[i]);
}

// GEMM: h = ns @ W via bf16 MFMA. 32 rows x 128 cols per block, 4 waves, wave
// w owns cols [w*32, w*32+32). NO LDS staging / NO barriers in the main loop:
// A loaded direct from global in two 16-deep pinned batches (16 KB/wave in
// flight), fp32->bf16 via v_cvt_pk_bf16_f32. L1 dedupes the 4-wave A overlap.
__global__ __launch_bounds__(256, 2) void k_gemm(
    const float* __restrict__ ns, const unsigned short* __restrict__ Wt,
    const float* __restrict__ ka, unsigned short* __restrict__ hb,
    float* __restrict__ a_src, float* __restrict__ a_dst)
{
    __shared__ char smem[32 * 136 * 2 + 1024];  // Ht[32][136] ushort + ka[256] f32
    float* ka_s = (float*)(smem + 32 * 136 * 2);
    const int t = threadIdx.x;
    const int lane = t & 63;
    const int w = t >> 6;
    const int row0 = blockIdx.x * 32;        // 3125 * 32 = 100000 exact
    const int lrow = lane & 15;
    const int khalf = lane >> 4;

    ka_s[t] = ka[t];

    // ---- B fragments: bfrag[nt][ks], (lane,elem)->k = khalf*8 + ks*32 + e ----
    short8 bfrag[2][8];
    {
        const int col0 = w * 32 + lrow;
        #pragma unroll
        for (int nt = 0; nt < 2; ++nt) {
            const unsigned short* wp = Wt + (size_t)(col0 + nt * 16) * 256 + khalf * 8;
            #pragma unroll
            for (int ks = 0; ks < 8; ++ks)
                bfrag[nt][ks] = *(const short8*)(wp + ks * 32);
        }
    }

    // ---- A batches: same (lane,elem)->k map as B. A0 = ksteps 0-3, A1 = 4-7 ----
    const float* arow[2];
    #pragma unroll
    for (int mt = 0; mt < 2; ++mt)
        arow[mt] = ns + (size_t)(row0 + mt * 16 + lrow) * FF + khalf * 8;

    f32x4 A0[16], A1[16];
    #pragma unroll
    for (int i = 0; i < 16; ++i) {
        const int mt = i >> 3, ks = (i >> 1) & 3, h = i & 1;
        A0[i] = *(const f32x4*)(arow[mt] + ks * 32 + h * 4);
    }
    #pragma unroll
    for (int i = 0; i < 16; ++i) {
        const int mt = i >> 3, ks = (i >> 1) & 3, h = i & 1;
        A1[i] = *(const f32x4*)(arow[mt] + 128 + ks * 32 + h * 4);
    }

    PIN8(bfrag[0][0], bfrag[0][1], bfrag[0][2], bfrag[0][3],
         bfrag[0][4], bfrag[0][5], bfrag[0][6], bfrag[0][7]);
    PIN8(bfrag[1][0], bfrag[1][1], bfrag[1][2], bfrag[1][3],
         bfrag[1][4], bfrag[1][5], bfrag[1][6], bfrag[1][7]);
    PIN8(A0[0], A0[1], A0[2], A0[3], A0[4], A0[5], A0[6], A0[7]);
    PIN8(A0[8], A0[9], A0[10], A0[11], A0[12], A0[13], A0[14], A0[15]);

    f32x4 acc[2][2];
    #pragma unroll
    for (int mt = 0; mt < 2; ++mt)
        #pragma unroll
        for (int nt = 0; nt < 2; ++nt)
            acc[mt][nt] = (f32x4){0.f, 0.f, 0.f, 0.f};

    // ---- half-K 0: ksteps 0-3 from A0 (A1 still in flight) ----
    #pragma unroll
    for (int ks = 0; ks < 4; ++ks) {
        short8 a[2];
        #pragma unroll
        for (int mt = 0; mt < 2; ++mt) {
            const f32x4 lo = A0[mt * 8 + ks * 2];
            const f32x4 hi = A0[mt * 8 + ks * 2 + 1];
            u32x4 u;
            u[0] = cvt_pk_bf16(lo[0], lo[1]);
            u[1] = cvt_pk_bf16(lo[2], lo[3]);
            u[2] = cvt_pk_bf16(hi[0], hi[1]);
            u[3] = cvt_pk_bf16(hi[2], hi[3]);
            a[mt] = __builtin_bit_cast(short8, u);
        }
        #pragma unroll
        for (int mt = 0; mt < 2; ++mt)
            #pragma unroll
            for (int nt = 0; nt < 2; ++nt)
                acc[mt][nt] = __builtin_amdgcn_mfma_f32_16x16x32_bf16(
                    a[mt], bfrag[nt][ks], acc[mt][nt], 0, 0, 0);
    }

    PIN8(A1[0], A1[1], A1[2], A1[3], A1[4], A1[5], A1[6], A1[7]);
    PIN8(A1[8], A1[9], A1[10], A1[11], A1[12], A1[13], A1[14], A1[15]);

    // ---- half-K 1: ksteps 4-7 from A1 ----
    #pragma unroll
    for (int ks = 0; ks < 4; ++ks) {
        short8 a[2];
        #pragma unroll
        for (int mt = 0; mt < 2; ++mt) {
            const f32x4 lo = A1[mt * 8 + ks * 2];
            const f32x4 hi = A1[mt * 8 + ks * 2 + 1];
            u32x4 u;
            u[0] = cvt_pk_bf16(lo[0], lo[1]);
            u[1] = cvt_pk_bf16(lo[2], lo[3]);
            u[2] = cvt_pk_bf16(hi[0], hi[1]);
            u[3] = cvt_pk_bf16(hi[2], hi[3]);
            a[mt] = __builtin_bit_cast(short8, u);
        }
        #pragma unroll
        for (int mt = 0; mt < 2; ++mt)
            #pragma unroll
            for (int nt = 0; nt < 2; ++nt)
                acc[mt][nt] = __builtin_amdgcn_mfma_f32_16x16x32_bf16(
                    a[mt], bfrag[nt][ks + 4], acc[mt][nt], 0, 0, 0);
    }

    // ---- acc -> Ht (stride 136 shorts breaks bank aliasing) ----
    unsigned short* Hs = (unsigned short*)smem;
    {
        const int wcol = w * 32;
        #pragma unroll
        for (int mt = 0; mt < 2; ++mt)
            #pragma unroll
            for (int nt = 0; nt < 2; ++nt)
                #pragma unroll
                for (int r = 0; r < 4; ++r) {
                    int row = mt * 16 + khalf * 4 + r;
                    int col = wcol + nt * 16 + lrow;
                    Hs[row * 136 + col] = f2bf(acc[mt][nt][r]);
                }
    }
    __syncthreads();

    // ---- coalesced hb store + attention dots (8 threads per row) ----
    {
        const int row = t >> 3, q8 = t & 7;
        const int gr = row0 + row;
        short8 hv0 = *(const short8*)(Hs + row * 136 + q8 * 16);
        short8 hv1 = *(const short8*)(Hs + row * 136 + q8 * 16 + 8);
        float ps = 0.f, pd = 0.f;
        #pragma unroll
        for (int e = 0; e < 8; ++e) {
            int c = q8 * 16 + e;
            ps = fmaf(bf2f((unsigned short)hv0[e]), ka_s[c], ps);
            pd = fmaf(bf2f((unsigned short)hv0[e]), ka_s[UU + c], pd);
            ps = fmaf(bf2f((unsigned short)hv1[e]), ka_s[c + 8], ps);
            pd = fmaf(bf2f((unsigned short)hv1[e]), ka_s[UU + c + 8], pd);
        }
        short8* op = (short8*)(hb + (size_t)gr * UU + q8 * 16);
        op[0] = hv0;
        op[1] = hv1;
        ps += __shfl_xor(ps, 1, 64); ps += __shfl_xor(ps, 2, 64); ps += __shfl_xor(ps, 4, 64);
        pd += __shfl_xor(pd, 1, 64); pd += __shfl_xor(pd, 2, 64); pd += __shfl_xor(pd, 4, 64);
        if (q8 == 0) { a_src[gr] = ps; a_dst[gr] = pd; }
    }
}

// Edge kernel: scores + per-node softmax -> packed nd[e] = (dst<<15) | norm_q15.
__global__ __launch_bounds__(256, 8) void k_edge(
    const int* __restrict__ edges, const float* __restrict__ ew,
    const float* __restrict__ a_src, const float* __restrict__ a_dst,
    uint32_t* __restrict__ nd)
{
    const int ei = blockIdx.x * 256 + threadIdx.x;
    const int n = ei >> 4;
    const int dst = edges[2 * ei + 1];
    const float w = ew[ei];
    const float x0 = w * (a_src[n] + a_dst[dst]);
    float x = x0 > 0.f ? x0 : 0.2f * x0;        // leaky_relu, slope 0.2
    x = fminf(2.f, fmaxf(-2.f, x));             // clip
    const float s = __expf(x);

    float ssum = s;                              // xor masks <16 stay in-group
    ssum += __shfl_xor(ssum, 1, 64);
    ssum += __shfl_xor(ssum, 2, 64);
    ssum += __shfl_xor(ssum, 4, 64);
    ssum += __shfl_xor(ssum, 8, 64);
    const float norm = s / ssum;

    uint32_t q15 = (uint32_t)(norm * 32768.f + 0.5f);
    if (q15 > 32767u) q15 = 32767u;
    nd[ei] = ((uint32_t)dst << 15) | q15;
}

// Aggregation: 4 nodes per wave, 16 lanes per node, lane q owns 16B (8 bf16
// dims). Gather via global_load_lds with PER-LANE source addresses: 16 async
// issues/wave = 16 KB in hardware flight, batching guaranteed by the DMA
// engine (no compiler discretion). Wave-private LDS -> zero barriers; one
// vmcnt(0) drain, then conflict-free ds_read_b128 + FMA.
__global__ __launch_bounds__(256, 2) void k_agg(
    const uint32_t* __restrict__ nd, const unsigned short* __restrict__ hb,
    float* __restrict__ out)
{
    __shared__ char lds[4][16][1024];  // [wave][j][64 lanes * 16B]
    const int t = threadIdx.x;
    const int lane = t & 63;
    const int wv = t >> 6;
    const int g = lane >> 4;
    const int q = lane & 15;
    const int n = blockIdx.x * 16 + wv * 4 + g;   // 6250*16 = 100000 exact

    const uint32_t v = nd[(size_t)n * DEG + q];   // coalesced: index = bid*256 + t
    const uint32_t dstB = (v >> 15) << 8;         // dst * 256 bytes
    const float normf = (float)(v & 32767u) * (1.f / 32768.f);
    const int gb = lane & 48;

    // issue all 16 gathers async: instr j loads edge j's row-segment for each
    // of the wave's 4 nodes (lane(g,q): src = hb + dst[g,j]*256 + q*16)
    const char* hbase = (const char*)hb + q * 16;
    #pragma unroll
    for (int j = 0; j < 16; ++j) {
        const uint32_t aj = __shfl(dstB, gb | j, 64);
        __builtin_amdgcn_global_load_lds(
            (const __attribute__((address_space(1))) void*)(hbase + aj),
            (__attribute__((address_space(3))) void*)(lds[wv][j]), 16, 0, 0);
    }

    float nf[16];
    #pragma unroll
    for (int j = 0; j < 16; ++j) nf[j] = __shfl(normf, gb | j, 64);

    asm volatile("s_waitcnt vmcnt(0)" ::: "memory");
    __builtin_amdgcn_sched_barrier(0);

    float acc[8];
    #pragma unroll
    for (int d = 0; d < 8; ++d) acc[d] = 0.f;
    #pragma unroll
    for (int j = 0; j < 16; ++j) {
        const u32x4 r = *(const u32x4*)(lds[wv][j] + lane * 16);
        acc[0] = fmaf(nf[j], __builtin_bit_cast(float, r[0] << 16), acc[0]);
        acc[1] = fmaf(nf[j], __builtin_bit_cast(float, r[0] & 0xffff0000u), acc[1]);
        acc[2] = fmaf(nf[j], __builtin_bit_cast(float, r[1] << 16), acc[2]);
        acc[3] = fmaf(nf[j], __builtin_bit_cast(float, r[1] & 0xffff0000u), acc[3]);
        acc[4] = fmaf(nf[j], __builtin_bit_cast(float, r[2] << 16), acc[4]);
        acc[5] = fmaf(nf[j], __builtin_bit_cast(float, r[2] & 0xffff0000u), acc[5]);
        acc[6] = fmaf(nf[j], __builtin_bit_cast(float, r[3] << 16), acc[6]);
        acc[7] = fmaf(nf[j], __builtin_bit_cast(float, r[3] & 0xffff0000u), acc[7]);
    }

    float* op = out + (size_t)n * UU + q * 8;
    float4 o0, o1;
    o0.x = acc[0]; o0.y = acc[1]; o0.z = acc[2]; o0.w = acc[3];
    o1.x = acc[4]; o1.y = acc[5]; o1.z = acc[6]; o1.w = acc[7];
    *(float4*)op = o0;
    *(float4*)(op + 4) = o1;
}

extern "C" void kernel_launch(void* const* d_in, const int* in_sizes, int n_in,
                              void* d_out, int out_size, void* d_ws, size_t ws_size,
                              hipStream_t stream) {
    const float* ns    = (const float*)d_in[0];  // [1, N, 256] f32
    const int*   edges = (const int*)d_in[1];    // [1, E, 2] i32, src sorted
    const float* ew    = (const float*)d_in[2];  // [1, E] f32
    const float* W     = (const float*)d_in[3];  // [256, 128] f32
    const float* ka    = (const float*)d_in[4];  // [256, 1] f32
    float* out = (float*)d_out;                  // [N, 128] f32

    char* ws = (char*)d_ws;
    unsigned short* hb = (unsigned short*)ws;                    // N*128 bf16 = 25.6 MB
    float* a_src = (float*)(ws + (size_t)NN * UU * 2);           // N f32
    float* a_dst = a_src + NN;                                   // N f32
    unsigned short* Wt = (unsigned short*)(ws + (size_t)NN * UU * 2 + 2 * (size_t)NN * 4);  // 64 KB
    uint32_t* nd = (uint32_t*)(ws + (size_t)NN * UU * 2 + 2 * (size_t)NN * 4 + 65536);      // E u32 = 6.4 MB

    k_convW<<<FF * UU / 256, 256, 0, stream>>>(W, Wt);                        // 128 blocks
    k_gemm<<<NN / 32, 256, 0, stream>>>(ns, Wt, ka, hb, a_src, a_dst);        // 3125 blocks
    k_edge<<<NN * DEG / 256, 256, 0, stream>>>(edges, ew, a_src, a_dst, nd);  // 6250 blocks
    k_agg<<<NN / 16, 256, 0, stream>>>(nd, hb, out);                          // 6250 blocks
}